// Round 1
// baseline (891.609 us; speedup 1.0000x reference)
//
#include <hip/hip_runtime.h>

#define NN 512
#define DD 64
#define BB 64
#define ND (NN * DD)          // 32768

// ---------------------------------------------------------------------------
// Generic 64-output-col GEMM with fused epilogue:
//   out[b,i,f] = alpha * sum_k A[b,i,k] * U[(b,z),k,f]  (+ beta*Vm[b,i,f]) (+ Zt[b,i,f]) (+ bias[f])
// Block: 64 rows x 64 cols, 256 threads, 4x4 register tile per thread.
// A tile stored transposed in LDS (At[kk][row]) so inner loop is 2x ds_read_b128 + 16 fma.
// ---------------------------------------------------------------------------
template <bool HAS_VM, bool HAS_Z, bool HAS_BIAS>
__global__ __launch_bounds__(256) void gemm64(
    const float* __restrict__ A, int lda, long aBatch,
    const float* __restrict__ U, long uBatch, long uZ,
    const float* __restrict__ Vm, const float* __restrict__ Zt,
    const float* __restrict__ bias,
    float alpha, float beta, int kdim,
    float* __restrict__ out, long outZ)
{
    const int b = blockIdx.y, z = blockIdx.z;
    const int i0 = blockIdx.x * 64;
    const float* __restrict__ Ab = A + (long)b * aBatch;
    const float* __restrict__ Ub = U + (long)b * uBatch + (long)z * uZ;
    float* __restrict__ outb = out + (long)z * outZ + (long)b * ND;

    __shared__ float At[32][68];   // transposed A tile; 68 keeps 16B alignment, spreads banks
    __shared__ float Ut[32][64];

    const int t = threadIdx.x;
    const int tx = t & 15, ty = t >> 4;
    float acc[4][4] = {};

    for (int k0 = 0; k0 < kdim; k0 += 32) {
        #pragma unroll
        for (int l = 0; l < 2; ++l) {
            const int idx = t + l * 256;            // 0..511
            const int r  = idx >> 3;                // 0..63
            const int c4 = (idx & 7) << 2;          // 0..28
            float4 v = *reinterpret_cast<const float4*>(Ab + (long)(i0 + r) * lda + (k0 + c4));
            At[c4 + 0][r] = v.x; At[c4 + 1][r] = v.y;
            At[c4 + 2][r] = v.z; At[c4 + 3][r] = v.w;
            const int rr = idx >> 4;                // 0..31
            const int cc = (idx & 15) << 2;         // 0..60
            float4 w = *reinterpret_cast<const float4*>(Ub + (long)(k0 + rr) * DD + cc);
            *reinterpret_cast<float4*>(&Ut[rr][cc]) = w;
        }
        __syncthreads();
        #pragma unroll
        for (int kk = 0; kk < 32; ++kk) {
            const float4 a = *reinterpret_cast<const float4*>(&At[kk][ty * 4]);
            const float4 u = *reinterpret_cast<const float4*>(&Ut[kk][tx * 4]);
            const float av[4] = {a.x, a.y, a.z, a.w};
            const float uv[4] = {u.x, u.y, u.z, u.w};
            #pragma unroll
            for (int i = 0; i < 4; ++i)
                #pragma unroll
                for (int j = 0; j < 4; ++j)
                    acc[i][j] = fmaf(av[i], uv[j], acc[i][j]);
        }
        __syncthreads();
    }

    #pragma unroll
    for (int i = 0; i < 4; ++i) {
        const int row = i0 + ty * 4 + i;
        const long base = (long)row * DD + tx * 4;
        float4 v;
        v.x = alpha * acc[i][0]; v.y = alpha * acc[i][1];
        v.z = alpha * acc[i][2]; v.w = alpha * acc[i][3];
        if (HAS_VM) {
            float4 m = *reinterpret_cast<const float4*>(Vm + (long)b * ND + base);
            v.x += beta * m.x; v.y += beta * m.y; v.z += beta * m.z; v.w += beta * m.w;
        }
        if (HAS_Z) {
            float4 zz = *reinterpret_cast<const float4*>(Zt + (long)b * ND + base);
            v.x += zz.x; v.y += zz.y; v.z += zz.z; v.w += zz.w;
        }
        if (HAS_BIAS) {
            v.x += bias[tx * 4 + 0]; v.y += bias[tx * 4 + 1];
            v.z += bias[tx * 4 + 2]; v.w += bias[tx * 4 + 3];
        }
        *reinterpret_cast<float4*>(outb + base) = v;
    }
}

// ---------------------------------------------------------------------------
// LayerNorm over last two dims ([N,D] per batch) + relu + mean/max pooling over N.
// One block (256 threads) per batch.
// ---------------------------------------------------------------------------
__global__ __launch_bounds__(256) void ln_pool(
    const float* __restrict__ pre, const float* __restrict__ gamma,
    const float* __restrict__ beta, float* __restrict__ h,
    float* __restrict__ zfeat, int zoff)
{
    const int b = blockIdx.x;
    const float* __restrict__ p = pre + (long)b * ND;
    const int t = threadIdx.x;

    float s = 0.f, s2 = 0.f;
    for (int i = t * 4; i < ND; i += 1024) {
        float4 v = *reinterpret_cast<const float4*>(p + i);
        s  += v.x + v.y + v.z + v.w;
        s2 += v.x * v.x + v.y * v.y + v.z * v.z + v.w * v.w;
    }
    #pragma unroll
    for (int off = 32; off > 0; off >>= 1) {
        s  += __shfl_down(s, off, 64);
        s2 += __shfl_down(s2, off, 64);
    }
    __shared__ float red[8];
    if ((t & 63) == 0) { red[(t >> 6) * 2] = s; red[(t >> 6) * 2 + 1] = s2; }
    __syncthreads();
    __shared__ float mu_s, rstd_s;
    if (t == 0) {
        float ts  = red[0] + red[2] + red[4] + red[6];
        float ts2 = red[1] + red[3] + red[5] + red[7];
        float mu  = ts * (1.f / ND);
        float var = ts2 * (1.f / ND) - mu * mu;
        mu_s = mu; rstd_s = rsqrtf(var + 1e-5f);
    }
    __syncthreads();
    const float mu = mu_s, rstd = rstd_s;

    const int f = t & 63, n0 = t >> 6;
    float sumf = 0.f, maxf = 0.f;   // post-relu values are >= 0
    for (int n = n0; n < NN; n += 4) {
        const int idx = n * DD + f;
        float v = (p[idx] - mu) * rstd * gamma[idx] + beta[idx];
        v = fmaxf(v, 0.f);
        h[(long)b * ND + idx] = v;
        sumf += v; maxf = fmaxf(maxf, v);
    }
    __shared__ float rs[256], rm[256];
    rs[t] = sumf; rm[t] = maxf;
    __syncthreads();
    if (t < 64) {
        float s4 = rs[t] + rs[t + 64] + rs[t + 128] + rs[t + 192];
        float m4 = fmaxf(fmaxf(rm[t], rm[t + 64]), fmaxf(rm[t + 128], rm[t + 192]));
        zfeat[b * 256 + zoff + t]      = s4 * (1.f / NN);
        zfeat[b * 256 + zoff + 64 + t] = m4;
    }
}

// ---------------------------------------------------------------------------
// AE[b,i,j] = relu(dot(X0[b,i,:], X0[b,j,:])), diagonal zeroed.
// (X0 X0^T is exactly symmetric and tiles (i,j)/(j,i) sum in identical order,
//  so 0.5*(AE+AE^T) is the identity here.)
// ---------------------------------------------------------------------------
__global__ __launch_bounds__(256) void outer_sym(
    const float* __restrict__ X0, float* __restrict__ AE)
{
    const int b = blockIdx.z;
    const int i0 = blockIdx.y * 64, j0 = blockIdx.x * 64;
    const float* __restrict__ Xb = X0 + (long)b * ND;
    __shared__ float Xi[64][68];
    __shared__ float Xj[64][68];
    const int t = threadIdx.x;
    const int tx = t & 15, ty = t >> 4;
    #pragma unroll
    for (int l = 0; l < 4; ++l) {
        const int idx = t + l * 256;        // 0..1023
        const int r  = idx >> 4;            // 0..63
        const int c4 = (idx & 15) << 2;     // 0..60
        float4 vi = *reinterpret_cast<const float4*>(Xb + (long)(i0 + r) * DD + c4);
        Xi[c4 + 0][r] = vi.x; Xi[c4 + 1][r] = vi.y; Xi[c4 + 2][r] = vi.z; Xi[c4 + 3][r] = vi.w;
        float4 vj = *reinterpret_cast<const float4*>(Xb + (long)(j0 + r) * DD + c4);
        Xj[c4 + 0][r] = vj.x; Xj[c4 + 1][r] = vj.y; Xj[c4 + 2][r] = vj.z; Xj[c4 + 3][r] = vj.w;
    }
    __syncthreads();
    float acc[4][4] = {};
    #pragma unroll
    for (int f = 0; f < 64; ++f) {
        const float4 a = *reinterpret_cast<const float4*>(&Xi[f][ty * 4]);
        const float4 u = *reinterpret_cast<const float4*>(&Xj[f][tx * 4]);
        const float av[4] = {a.x, a.y, a.z, a.w};
        const float uv[4] = {u.x, u.y, u.z, u.w};
        #pragma unroll
        for (int i = 0; i < 4; ++i)
            #pragma unroll
            for (int j = 0; j < 4; ++j)
                acc[i][j] = fmaf(av[i], uv[j], acc[i][j]);
    }
    #pragma unroll
    for (int i = 0; i < 4; ++i) {
        const int row = i0 + ty * 4 + i;
        const int colbase = j0 + tx * 4;
        float4 v;
        v.x = fmaxf(acc[i][0], 0.f);
        v.y = fmaxf(acc[i][1], 0.f);
        v.z = fmaxf(acc[i][2], 0.f);
        v.w = fmaxf(acc[i][3], 0.f);
        if (row == colbase + 0) v.x = 0.f;
        if (row == colbase + 1) v.y = 0.f;
        if (row == colbase + 2) v.z = 0.f;
        if (row == colbase + 3) v.w = 0.f;
        *reinterpret_cast<float4*>(AE + (long)b * NN * NN + (long)row * NN + colbase) = v;
    }
}

// ---------------------------------------------------------------------------
// Tiny MLP heads. One 64-thread block per batch row.
// ---------------------------------------------------------------------------
__global__ __launch_bounds__(64) void heads(
    const float* __restrict__ zfeat,
    const float* __restrict__ p1w, const float* __restrict__ p1b,
    const float* __restrict__ p2w, const float* __restrict__ p2b,
    const float* __restrict__ p3w, const float* __restrict__ p3b,
    const float* __restrict__ s1w, const float* __restrict__ s1b,
    const float* __restrict__ s2w, const float* __restrict__ s2b,
    const float* __restrict__ p4w, const float* __restrict__ p4b,
    float* __restrict__ outc, float* __restrict__ outs)
{
    const int b = blockIdx.x, t = threadIdx.x;
    __shared__ float zf[256], v1[64], v2[64], lg[2];
    for (int i = t; i < 256; i += 64) zf[i] = zfeat[b * 256 + i];
    __syncthreads();

    float a = p1b[t];
    for (int z = 0; z < 256; ++z) a = fmaf(zf[z], p1w[z * 64 + t], a);
    v1[t] = a >= 0.f ? a : 0.2f * a;
    __syncthreads();
    float a2 = p2b[t];
    for (int z = 0; z < 64; ++z) a2 = fmaf(v1[z], p2w[z * 64 + t], a2);
    v2[t] = a2 >= 0.f ? a2 : 0.2f * a2;
    __syncthreads();
    if (t < 4) {
        float a3 = p3b[t];
        for (int z = 0; z < 64; ++z) a3 = fmaf(v2[z], p3w[z * 4 + t], a3);
        outc[b * 4 + t] = 1.f / (1.f + expf(-a3));
    }
    __syncthreads();

    float c = s1b[t];
    for (int z = 0; z < 256; ++z) c = fmaf(zf[z], s1w[z * 64 + t], c);
    v1[t] = c >= 0.f ? c : 0.2f * c;
    __syncthreads();
    float c2 = s2b[t];
    for (int z = 0; z < 64; ++z) c2 = fmaf(v1[z], s2w[z * 64 + t], c2);
    v2[t] = c2 >= 0.f ? c2 : 0.2f * c2;
    __syncthreads();
    if (t < 2) {
        float d = p4b[t];
        for (int z = 0; z < 64; ++z) d = fmaf(v2[z], p4w[z * 2 + t], d);
        lg[t] = d;
    }
    __syncthreads();
    if (t < 2) {
        float m = fmaxf(lg[0], lg[1]);
        float lse = m + logf(expf(lg[0] - m) + expf(lg[1] - m));
        outs[b * 2 + t] = lg[t] - lse;
    }
}

// ---------------------------------------------------------------------------
// Clenshaw evaluation of sum_k T_k(A) (x W[k]) per stage:
//   Z_k = x @ W[k]                     (one batched GEMM pass)
//   b5=Z5; b4=2A b5+Z4; b3=2A b4-b5+Z3; b2=2A b3-b4+Z2; b1=2A b2-b3+Z1
//   S = A b1 - b2 + Z0 + bias
// Buffers: Zs (6*B*N*D) + bufA/bufB live inside d_out's AE region (dead before
// the final AE write); bufC / h / zfeat in d_ws (~17 MB used).
// ---------------------------------------------------------------------------
extern "C" void kernel_launch(void* const* d_in, const int* in_sizes, int n_in,
                              void* d_out, int out_size, void* d_ws, size_t ws_size,
                              hipStream_t stream)
{
    const float* A   = (const float*)d_in[0];
    const float* X   = (const float*)d_in[1];
    const float* W1  = (const float*)d_in[2];
    const float* b1v = (const float*)d_in[3];
    const float* W2  = (const float*)d_in[4];
    const float* b2v = (const float*)d_in[5];
    const float* W3  = (const float*)d_in[6];
    const float* b3v = (const float*)d_in[7];
    const float* g1  = (const float*)d_in[8];
    const float* bt1 = (const float*)d_in[9];
    const float* g2  = (const float*)d_in[10];
    const float* bt2 = (const float*)d_in[11];
    const float* p1w = (const float*)d_in[12];
    const float* p1b = (const float*)d_in[13];
    const float* p2w = (const float*)d_in[14];
    const float* p2b = (const float*)d_in[15];
    const float* p3w = (const float*)d_in[16];
    const float* p3b = (const float*)d_in[17];
    const float* s1w = (const float*)d_in[18];
    const float* s1b = (const float*)d_in[19];
    const float* s2w = (const float*)d_in[20];
    const float* s2b = (const float*)d_in[21];
    const float* p4w = (const float*)d_in[22];
    const float* p4b = (const float*)d_in[23];

    float* out   = (float*)d_out;
    const long BND = (long)BB * ND;              // 2,097,152
    float* Zs    = out;                          // [6][B][N][D] = 12.58M floats (< 16.78M AE)
    float* bufA  = out + 6 * BND;                // 12,582,912
    float* bufB  = out + 7 * BND;                // 14,680,064 (ends exactly at AE size)
    float* ws    = (float*)d_ws;
    float* bufC  = ws;                           // 2,097,152 floats
    float* hbuf  = ws + BND;                     // 2,097,152 floats
    float* zfeat = ws + 2 * BND;                 // 16,384 floats
    float* outc  = out + (long)BB * NN * NN;     // 16,777,216
    float* outsc = outc + BB * 4;

    const dim3 blk(256);
    const long ABATCH = (long)NN * NN;

    auto zgemm = [&](const float* x, int lda, long aB, const float* W, int kdim) {
        gemm64<false, false, false><<<dim3(8, 64, 6), blk, 0, stream>>>(
            x, lda, aB, W, 0L, (long)kdim * DD, nullptr, nullptr, nullptr,
            1.0f, 0.0f, kdim, Zs, BND);
    };
    auto cheb = [&](const float* bias, float* xout) {
        // b4 = 2 A Z5 + Z4
        gemm64<false, true, false><<<dim3(8, 64, 1), blk, 0, stream>>>(
            A, NN, ABATCH, Zs + 5 * BND, (long)ND, 0L, nullptr, Zs + 4 * BND, nullptr,
            2.0f, 0.0f, NN, bufA, 0L);
        // b3 = 2 A b4 - Z5 + Z3
        gemm64<true, true, false><<<dim3(8, 64, 1), blk, 0, stream>>>(
            A, NN, ABATCH, bufA, (long)ND, 0L, Zs + 5 * BND, Zs + 3 * BND, nullptr,
            2.0f, -1.0f, NN, bufB, 0L);
        // b2 = 2 A b3 - b4 + Z2
        gemm64<true, true, false><<<dim3(8, 64, 1), blk, 0, stream>>>(
            A, NN, ABATCH, bufB, (long)ND, 0L, bufA, Zs + 2 * BND, nullptr,
            2.0f, -1.0f, NN, bufC, 0L);
        // b1 = 2 A b2 - b3 + Z1
        gemm64<true, true, false><<<dim3(8, 64, 1), blk, 0, stream>>>(
            A, NN, ABATCH, bufC, (long)ND, 0L, bufB, Zs + 1 * BND, nullptr,
            2.0f, -1.0f, NN, bufA, 0L);
        // S = A b1 - b2 + Z0 + bias
        gemm64<true, true, true><<<dim3(8, 64, 1), blk, 0, stream>>>(
            A, NN, ABATCH, bufA, (long)ND, 0L, bufC, Zs + 0 * BND, bias,
            1.0f, -1.0f, NN, xout, 0L);
    };

    // stage 1: cheb(X, A, W1) -> LN -> relu -> pool
    zgemm(X, NN, ABATCH, W1, NN);
    cheb(b1v, bufB);
    ln_pool<<<dim3(64), blk, 0, stream>>>(bufB, g1, bt1, hbuf, zfeat, 0);

    // stage 2: cheb(h1, A, W2) -> LN -> relu -> pool
    zgemm(hbuf, DD, (long)ND, W2, DD);
    cheb(b2v, bufB);
    ln_pool<<<dim3(64), blk, 0, stream>>>(bufB, g2, bt2, hbuf, zfeat, 128);

    // stage 3: X0 = cheb(h2, A, W3) + b3   (no LN) -> hbuf (ws, safe vs AE write)
    zgemm(hbuf, DD, (long)ND, W3, DD);
    cheb(b3v, hbuf);

    // AE = relu(X0 X0^T), zero diag
    outer_sym<<<dim3(8, 8, 64), blk, 0, stream>>>(hbuf, out);

    // heads
    heads<<<dim3(64), dim3(64), 0, stream>>>(
        zfeat, p1w, p1b, p2w, p2b, p3w, p3b, s1w, s1b, s2w, s2b, p4w, p4b, outc, outsc);
}

// Round 2
// 571.838 us; speedup vs baseline: 1.5592x; 1.5592x over previous
//
#include <hip/hip_runtime.h>

#define NN 512
#define DD 64
#define BB 64
#define ND (NN * DD)          // 32768

typedef __bf16 bf16x8 __attribute__((ext_vector_type(8)));
typedef float  f32x4  __attribute__((ext_vector_type(4)));

// fp32 -> bf16 round-to-nearest-even (bit trick; finite inputs only)
__device__ __forceinline__ unsigned short f2bf(float x) {
    unsigned int u = __float_as_uint(x);
    unsigned int r = u + 0x7fffu + ((u >> 16) & 1u);
    return (unsigned short)(r >> 16);
}
// split x into hi+lo bf16 pair, per float4
__device__ __forceinline__ void cvt4(const float4& x, ushort4& h, ushort4& l) {
    float xs[4] = {x.x, x.y, x.z, x.w};
    unsigned short hh[4], ll[4];
#pragma unroll
    for (int i = 0; i < 4; ++i) {
        hh[i] = f2bf(xs[i]);
        float hf = __uint_as_float(((unsigned int)hh[i]) << 16);
        ll[i] = f2bf(xs[i] - hf);
    }
    h = make_ushort4(hh[0], hh[1], hh[2], hh[3]);
    l = make_ushort4(ll[0], ll[1], ll[2], ll[3]);
}
__device__ __forceinline__ bf16x8 ld_bf8(const unsigned short* p) {
    int4 v = *reinterpret_cast<const int4*>(p);
    return __builtin_bit_cast(bf16x8, v);
}
__device__ __forceinline__ f32x4 mfma16(bf16x8 a, bf16x8 b, f32x4 c) {
    return __builtin_amdgcn_mfma_f32_16x16x32_bf16(a, b, c, 0, 0, 0);
}
// LDS tile [64 rows][64 bf16], XOR-swizzled 16B groups: write idx for float4 (r, c: c-th float4 of row)
__device__ __forceinline__ int swzW(int r, int c) {
    return r * 64 + (((c >> 1) ^ (r & 7)) << 3) + ((c & 1) << 2);
}
// read idx for 8-bf16 octet `oct` (0..7) of row r
__device__ __forceinline__ int swzR(int r, int oct) {
    return r * 64 + ((oct ^ (r & 7)) << 3);
}

// ---------------------------------------------------------------------------
// MFMA GEMM, out[b,z,i,f] = alpha * sum_k A[b,i,k]*Bop[(b,z),f,k]
//                           (+ beta*Vm) (+ Zt) (+ bias[f])
// A: fp32 row-major [.., kdim] (lda). Bop: fp32 col-major [64][kdim].
// Vm/Zt: fp32 col-major [64][512], batch stride ND. out: col-major [64][512]
// (or row-major [512][64] if OUT_ROW). Internally bf16 hi/lo, 3-MFMA per MAC.
// Block 256 thr = 4 waves (2x2), out tile 64x64, BK=64.
// ---------------------------------------------------------------------------
template <bool HAS_VM, bool HAS_Z, bool HAS_BIAS, bool OUT_ROW>
__global__ __launch_bounds__(256) void gemm_mfma(
    const float* __restrict__ A, int lda, long aBatch,
    const float* __restrict__ Bop, long bBatch, long bZ,
    const float* __restrict__ Vm, const float* __restrict__ Zt,
    const float* __restrict__ bias, float alpha, float beta,
    int kdim, float* __restrict__ out, long outZ)
{
    const int b = blockIdx.y, z = blockIdx.z;
    const int i0 = blockIdx.x * 64;
    const float* __restrict__ Ab = A + (long)b * aBatch;
    const float* __restrict__ Bb = Bop + (long)b * bBatch + (long)z * bZ;

    __shared__ __align__(16) unsigned short sAh[64 * 64];
    __shared__ __align__(16) unsigned short sAl[64 * 64];
    __shared__ __align__(16) unsigned short sBh[64 * 64];
    __shared__ __align__(16) unsigned short sBl[64 * 64];

    const int t = threadIdx.x;
    const int w = t >> 6, lane = t & 63;
    const int wr = w >> 1, wc = w & 1;
    const int lr = lane & 15, lg = lane >> 4;

    f32x4 acc[2][2];
#pragma unroll
    for (int m = 0; m < 2; ++m)
#pragma unroll
        for (int n = 0; n < 2; ++n) acc[m][n] = f32x4{0.f, 0.f, 0.f, 0.f};

    float4 ra[4], rb[4];
    auto loadAB = [&](int k0) {
#pragma unroll
        for (int l = 0; l < 4; ++l) {
            int q = t + l * 256;
            int r = q >> 4, c = q & 15;
            ra[l] = *reinterpret_cast<const float4*>(Ab + (long)(i0 + r) * lda + k0 + c * 4);
            rb[l] = *reinterpret_cast<const float4*>(Bb + (long)r * kdim + k0 + c * 4);
        }
    };
    auto cvtWrite = [&]() {
#pragma unroll
        for (int l = 0; l < 4; ++l) {
            int q = t + l * 256;
            int r = q >> 4, c = q & 15;
            int idx = swzW(r, c);
            ushort4 h4, l4;
            cvt4(ra[l], h4, l4);
            *reinterpret_cast<ushort4*>(&sAh[idx]) = h4;
            *reinterpret_cast<ushort4*>(&sAl[idx]) = l4;
            cvt4(rb[l], h4, l4);
            *reinterpret_cast<ushort4*>(&sBh[idx]) = h4;
            *reinterpret_cast<ushort4*>(&sBl[idx]) = l4;
        }
    };

    loadAB(0);
    const int steps = kdim >> 6;
    for (int s = 0; s < steps; ++s) {
        if (s) __syncthreads();
        cvtWrite();
        __syncthreads();
        if (s + 1 < steps) loadAB((s + 1) << 6);
#pragma unroll
        for (int c2 = 0; c2 < 2; ++c2) {
            bf16x8 a_h[2], a_l[2], b_h[2], b_l[2];
#pragma unroll
            for (int m = 0; m < 2; ++m) {
                int row = wr * 32 + m * 16 + lr;
                int oct = (c2 << 2) + lg;
                a_h[m] = ld_bf8(&sAh[swzR(row, oct)]);
                a_l[m] = ld_bf8(&sAl[swzR(row, oct)]);
                int col = wc * 32 + m * 16 + lr;
                b_h[m] = ld_bf8(&sBh[swzR(col, oct)]);
                b_l[m] = ld_bf8(&sBl[swzR(col, oct)]);
            }
#pragma unroll
            for (int m = 0; m < 2; ++m)
#pragma unroll
                for (int n = 0; n < 2; ++n) {
                    acc[m][n] = mfma16(a_h[m], b_h[n], acc[m][n]);
                    acc[m][n] = mfma16(a_h[m], b_l[n], acc[m][n]);
                    acc[m][n] = mfma16(a_l[m], b_h[n], acc[m][n]);
                }
        }
    }

    // epilogue: C/D frag (verified m89/m91): col = lane&15, row = (lane>>4)*4 + reg
    float* __restrict__ outb = OUT_ROW ? (out + (long)b * ND)
                                       : (out + (long)z * outZ + (long)b * ND);
#pragma unroll
    for (int m = 0; m < 2; ++m) {
        const int nb = i0 + wr * 32 + m * 16 + lg * 4;   // 4 consecutive output rows
#pragma unroll
        for (int n = 0; n < 2; ++n) {
            const int f = wc * 32 + n * 16 + lr;          // output col (feature)
            float4 v;
            v.x = alpha * acc[m][n][0]; v.y = alpha * acc[m][n][1];
            v.z = alpha * acc[m][n][2]; v.w = alpha * acc[m][n][3];
            if (HAS_VM) {
                float4 mv = *reinterpret_cast<const float4*>(Vm + (long)b * ND + (long)f * NN + nb);
                v.x += beta * mv.x; v.y += beta * mv.y; v.z += beta * mv.z; v.w += beta * mv.w;
            }
            if (HAS_Z) {
                float4 zz = *reinterpret_cast<const float4*>(Zt + (long)b * ND + (long)f * NN + nb);
                v.x += zz.x; v.y += zz.y; v.z += zz.z; v.w += zz.w;
            }
            if (HAS_BIAS) {
                float bf = bias[f];
                v.x += bf; v.y += bf; v.z += bf; v.w += bf;
            }
            if (OUT_ROW) {
                outb[(long)(nb + 0) * DD + f] = v.x;
                outb[(long)(nb + 1) * DD + f] = v.y;
                outb[(long)(nb + 2) * DD + f] = v.z;
                outb[(long)(nb + 3) * DD + f] = v.w;
            } else {
                *reinterpret_cast<float4*>(outb + (long)f * NN + nb) = v;
            }
        }
    }
}

// ---------------------------------------------------------------------------
// AE[b,i,j] = relu(dot(X0[b,i,:], X0[b,j,:])), diag zeroed. X0 row-major [512][64].
// Exactly symmetric construction -> 0.5*(AE+AE^T) is identity.
// ---------------------------------------------------------------------------
__global__ __launch_bounds__(256) void outer_mfma(
    const float* __restrict__ X0, float* __restrict__ AE)
{
    const int b = blockIdx.z;
    const int j0 = blockIdx.x * 64, i0 = blockIdx.y * 64;
    const float* __restrict__ Xb = X0 + (long)b * ND;

    __shared__ __align__(16) unsigned short sIh[64 * 64];
    __shared__ __align__(16) unsigned short sIl[64 * 64];
    __shared__ __align__(16) unsigned short sJh[64 * 64];
    __shared__ __align__(16) unsigned short sJl[64 * 64];

    const int t = threadIdx.x;
    const int w = t >> 6, lane = t & 63;
    const int wr = w >> 1, wc = w & 1;
    const int lr = lane & 15, lg = lane >> 4;

#pragma unroll
    for (int l = 0; l < 4; ++l) {
        int q = t + l * 256;
        int r = q >> 4, c = q & 15;
        int idx = swzW(r, c);
        ushort4 h4, l4;
        float4 vi = *reinterpret_cast<const float4*>(Xb + (long)(i0 + r) * DD + c * 4);
        cvt4(vi, h4, l4);
        *reinterpret_cast<ushort4*>(&sIh[idx]) = h4;
        *reinterpret_cast<ushort4*>(&sIl[idx]) = l4;
        float4 vj = *reinterpret_cast<const float4*>(Xb + (long)(j0 + r) * DD + c * 4);
        cvt4(vj, h4, l4);
        *reinterpret_cast<ushort4*>(&sJh[idx]) = h4;
        *reinterpret_cast<ushort4*>(&sJl[idx]) = l4;
    }
    __syncthreads();

    f32x4 acc[2][2];
#pragma unroll
    for (int m = 0; m < 2; ++m)
#pragma unroll
        for (int n = 0; n < 2; ++n) acc[m][n] = f32x4{0.f, 0.f, 0.f, 0.f};

#pragma unroll
    for (int c2 = 0; c2 < 2; ++c2) {
        bf16x8 a_h[2], a_l[2], b_h[2], b_l[2];
#pragma unroll
        for (int m = 0; m < 2; ++m) {
            int row = wr * 32 + m * 16 + lr;
            int oct = (c2 << 2) + lg;
            a_h[m] = ld_bf8(&sIh[swzR(row, oct)]);
            a_l[m] = ld_bf8(&sIl[swzR(row, oct)]);
            int col = wc * 32 + m * 16 + lr;
            b_h[m] = ld_bf8(&sJh[swzR(col, oct)]);
            b_l[m] = ld_bf8(&sJl[swzR(col, oct)]);
        }
#pragma unroll
        for (int m = 0; m < 2; ++m)
#pragma unroll
            for (int n = 0; n < 2; ++n) {
                acc[m][n] = mfma16(a_h[m], b_h[n], acc[m][n]);
                acc[m][n] = mfma16(a_h[m], b_l[n], acc[m][n]);
                acc[m][n] = mfma16(a_l[m], b_h[n], acc[m][n]);
            }
    }

    float* __restrict__ AEb = AE + (long)b * NN * NN;
#pragma unroll
    for (int m = 0; m < 2; ++m) {
        const int ib = i0 + wr * 32 + m * 16 + lg * 4;
#pragma unroll
        for (int n = 0; n < 2; ++n) {
            const int jc = j0 + wc * 32 + n * 16 + lr;
#pragma unroll
            for (int jj = 0; jj < 4; ++jj) {
                float v = fmaxf(acc[m][n][jj], 0.f);
                if (ib + jj == jc) v = 0.f;
                AEb[(long)(ib + jj) * NN + jc] = v;
            }
        }
    }
}

// ---------------------------------------------------------------------------
// LayerNorm over [N,D] + relu + mean/max pool over N.
// pre: fp32 col-major [64][512] per batch. h: fp32 row-major [512][64].
// gamma/beta: row-major [512][64]. One 256-thr block per batch.
// ---------------------------------------------------------------------------
__global__ __launch_bounds__(256) void ln_pool(
    const float* __restrict__ pre, const float* __restrict__ gamma,
    const float* __restrict__ beta, float* __restrict__ h,
    float* __restrict__ zfeat, int zoff)
{
    const int b = blockIdx.x;
    const float* __restrict__ p = pre + (long)b * ND;
    const int t = threadIdx.x;

    float s = 0.f, s2 = 0.f;
    for (int i = t * 4; i < ND; i += 1024) {
        float4 v = *reinterpret_cast<const float4*>(p + i);
        s  += v.x + v.y + v.z + v.w;
        s2 += v.x * v.x + v.y * v.y + v.z * v.z + v.w * v.w;
    }
#pragma unroll
    for (int off = 32; off > 0; off >>= 1) {
        s  += __shfl_down(s, off, 64);
        s2 += __shfl_down(s2, off, 64);
    }
    __shared__ float red[8];
    if ((t & 63) == 0) { red[(t >> 6) * 2] = s; red[(t >> 6) * 2 + 1] = s2; }
    __syncthreads();
    __shared__ float mu_s, rstd_s;
    if (t == 0) {
        float ts  = red[0] + red[2] + red[4] + red[6];
        float ts2 = red[1] + red[3] + red[5] + red[7];
        float mu  = ts * (1.f / ND);
        float var = ts2 * (1.f / ND) - mu * mu;
        mu_s = mu; rstd_s = rsqrtf(var + 1e-5f);
    }
    __syncthreads();
    const float mu = mu_s, rstd = rstd_s;

    const int f4 = (t & 15) * 4, nt = t >> 4;
    float sum4[4] = {0.f, 0.f, 0.f, 0.f};
    float max4[4] = {0.f, 0.f, 0.f, 0.f};   // post-relu >= 0
    for (int n = nt; n < NN; n += 16) {
        float4 g4 = *reinterpret_cast<const float4*>(gamma + (long)n * DD + f4);
        float4 be = *reinterpret_cast<const float4*>(beta  + (long)n * DD + f4);
        float4 v;
        v.x = fmaxf((p[(long)(f4 + 0) * NN + n] - mu) * rstd * g4.x + be.x, 0.f);
        v.y = fmaxf((p[(long)(f4 + 1) * NN + n] - mu) * rstd * g4.y + be.y, 0.f);
        v.z = fmaxf((p[(long)(f4 + 2) * NN + n] - mu) * rstd * g4.z + be.z, 0.f);
        v.w = fmaxf((p[(long)(f4 + 3) * NN + n] - mu) * rstd * g4.w + be.w, 0.f);
        *reinterpret_cast<float4*>(h + (long)b * ND + (long)n * DD + f4) = v;
        sum4[0] += v.x; sum4[1] += v.y; sum4[2] += v.z; sum4[3] += v.w;
        max4[0] = fmaxf(max4[0], v.x); max4[1] = fmaxf(max4[1], v.y);
        max4[2] = fmaxf(max4[2], v.z); max4[3] = fmaxf(max4[3], v.w);
    }
    __shared__ float rs[16][64], rm[16][64];
#pragma unroll
    for (int j = 0; j < 4; ++j) { rs[nt][f4 + j] = sum4[j]; rm[nt][f4 + j] = max4[j]; }
    __syncthreads();
    if (t < 64) {
        float ss = 0.f, mm = 0.f;
#pragma unroll
        for (int k = 0; k < 16; ++k) { ss += rs[k][t]; mm = fmaxf(mm, rm[k][t]); }
        zfeat[b * 256 + zoff + t]      = ss * (1.f / NN);
        zfeat[b * 256 + zoff + 64 + t] = mm;
    }
}

// ---------------------------------------------------------------------------
// W[z][kdim][64] row-major -> Wt[z][64][kdim] (tiny)
// ---------------------------------------------------------------------------
__global__ void transW(const float* __restrict__ W, float* __restrict__ Wt,
                       int kdim, int total)
{
    int o = blockIdx.x * 256 + threadIdx.x;
    if (o >= total) return;
    int per = 64 * kdim;
    int zz = o / per, r = o % per;
    int f = r / kdim, k = r % kdim;
    Wt[o] = W[((long)zz * kdim + k) * 64 + f];
}

// ---------------------------------------------------------------------------
// Tiny MLP heads. One 64-thread block per batch row.
// ---------------------------------------------------------------------------
__global__ __launch_bounds__(64) void heads(
    const float* __restrict__ zfeat,
    const float* __restrict__ p1w, const float* __restrict__ p1b,
    const float* __restrict__ p2w, const float* __restrict__ p2b,
    const float* __restrict__ p3w, const float* __restrict__ p3b,
    const float* __restrict__ s1w, const float* __restrict__ s1b,
    const float* __restrict__ s2w, const float* __restrict__ s2b,
    const float* __restrict__ p4w, const float* __restrict__ p4b,
    float* __restrict__ outc, float* __restrict__ outs)
{
    const int b = blockIdx.x, t = threadIdx.x;
    __shared__ float zf[256], v1[64], v2[64], lg[2];
    for (int i = t; i < 256; i += 64) zf[i] = zfeat[b * 256 + i];
    __syncthreads();

    float a = p1b[t];
    for (int z = 0; z < 256; ++z) a = fmaf(zf[z], p1w[z * 64 + t], a);
    v1[t] = a >= 0.f ? a : 0.2f * a;
    __syncthreads();
    float a2 = p2b[t];
    for (int z = 0; z < 64; ++z) a2 = fmaf(v1[z], p2w[z * 64 + t], a2);
    v2[t] = a2 >= 0.f ? a2 : 0.2f * a2;
    __syncthreads();
    if (t < 4) {
        float a3 = p3b[t];
        for (int z = 0; z < 64; ++z) a3 = fmaf(v2[z], p3w[z * 4 + t], a3);
        outc[b * 4 + t] = 1.f / (1.f + expf(-a3));
    }
    __syncthreads();

    float c = s1b[t];
    for (int z = 0; z < 256; ++z) c = fmaf(zf[z], s1w[z * 64 + t], c);
    v1[t] = c >= 0.f ? c : 0.2f * c;
    __syncthreads();
    float c2 = s2b[t];
    for (int z = 0; z < 64; ++z) c2 = fmaf(v1[z], s2w[z * 64 + t], c2);
    v2[t] = c2 >= 0.f ? c2 : 0.2f * c2;
    __syncthreads();
    if (t < 2) {
        float d = p4b[t];
        for (int z = 0; z < 64; ++z) d = fmaf(v2[z], p4w[z * 2 + t], d);
        lg[t] = d;
    }
    __syncthreads();
    if (t < 2) {
        float m = fmaxf(lg[0], lg[1]);
        float lse = m + logf(expf(lg[0] - m) + expf(lg[1] - m));
        outs[b * 2 + t] = lg[t] - lse;
    }
}

// ---------------------------------------------------------------------------
// Clenshaw: b5=Z5; b4=2A Z5+Z4; b3=2A b4-Z5+Z3; b2=2A b3-b4+Z2; b1=2A b2-b3+Z1;
// S = A b1 - b2 + Z0 + bias.   Zs/bufA/bufB in d_out (dead before AE write);
// bufC(/W1t)/h/zfeat/W2t/W3t in d_ws (~17 MB).
// ---------------------------------------------------------------------------
extern "C" void kernel_launch(void* const* d_in, const int* in_sizes, int n_in,
                              void* d_out, int out_size, void* d_ws, size_t ws_size,
                              hipStream_t stream)
{
    const float* A   = (const float*)d_in[0];
    const float* X   = (const float*)d_in[1];
    const float* W1  = (const float*)d_in[2];
    const float* b1v = (const float*)d_in[3];
    const float* W2  = (const float*)d_in[4];
    const float* b2v = (const float*)d_in[5];
    const float* W3  = (const float*)d_in[6];
    const float* b3v = (const float*)d_in[7];
    const float* g1  = (const float*)d_in[8];
    const float* bt1 = (const float*)d_in[9];
    const float* g2  = (const float*)d_in[10];
    const float* bt2 = (const float*)d_in[11];
    const float* p1w = (const float*)d_in[12];
    const float* p1b = (const float*)d_in[13];
    const float* p2w = (const float*)d_in[14];
    const float* p2b = (const float*)d_in[15];
    const float* p3w = (const float*)d_in[16];
    const float* p3b = (const float*)d_in[17];
    const float* s1w = (const float*)d_in[18];
    const float* s1b = (const float*)d_in[19];
    const float* s2w = (const float*)d_in[20];
    const float* s2b = (const float*)d_in[21];
    const float* p4w = (const float*)d_in[22];
    const float* p4b = (const float*)d_in[23];

    float* out   = (float*)d_out;
    const long BND = (long)BB * ND;              // 2,097,152
    float* Zs    = out;                          // [6][B][64][512] col-major
    float* bufA  = out + 6 * BND;
    float* bufB  = out + 7 * BND;                // ends exactly at AE size
    float* ws    = (float*)d_ws;
    float* bufC  = ws;                           // 2.1M floats
    float* W1t   = ws;                           // alias bufC (dead before bufC written)
    float* hbuf  = ws + BND;                     // 2.1M floats (h, then X0)
    float* zfeat = ws + 2 * BND;                 // 16384
    float* W2t   = ws + 2 * BND + 16384;         // 24576
    float* W3t   = W2t + 24576;                  // 24576
    float* outc  = out + (long)BB * NN * NN;
    float* outsc = outc + BB * 4;

    const dim3 blk(256);
    const long ABATCH = (long)NN * NN;

    // transpose W's to col-major [z][64][kdim]
    transW<<<dim3((6 * NN * DD + 255) / 256), blk, 0, stream>>>(W1, W1t, NN, 6 * NN * DD);
    transW<<<dim3((6 * DD * DD + 255) / 256), blk, 0, stream>>>(W2, W2t, DD, 6 * DD * DD);
    transW<<<dim3((6 * DD * DD + 255) / 256), blk, 0, stream>>>(W3, W3t, DD, 6 * DD * DD);

    auto cheb = [&](const float* bias, float* xout, bool rowOut) {
        gemm_mfma<false, true, false, false><<<dim3(8, 64, 1), blk, 0, stream>>>(
            A, NN, ABATCH, Zs + 5 * BND, (long)ND, 0L, nullptr, Zs + 4 * BND, nullptr,
            2.f, 0.f, NN, bufA, 0L);
        gemm_mfma<true, true, false, false><<<dim3(8, 64, 1), blk, 0, stream>>>(
            A, NN, ABATCH, bufA, (long)ND, 0L, Zs + 5 * BND, Zs + 3 * BND, nullptr,
            2.f, -1.f, NN, bufB, 0L);
        gemm_mfma<true, true, false, false><<<dim3(8, 64, 1), blk, 0, stream>>>(
            A, NN, ABATCH, bufB, (long)ND, 0L, bufA, Zs + 2 * BND, nullptr,
            2.f, -1.f, NN, bufC, 0L);
        gemm_mfma<true, true, false, false><<<dim3(8, 64, 1), blk, 0, stream>>>(
            A, NN, ABATCH, bufC, (long)ND, 0L, bufB, Zs + 1 * BND, nullptr,
            2.f, -1.f, NN, bufA, 0L);
        if (rowOut)
            gemm_mfma<true, true, true, true><<<dim3(8, 64, 1), blk, 0, stream>>>(
                A, NN, ABATCH, bufA, (long)ND, 0L, bufC, Zs + 0 * BND, bias,
                1.f, -1.f, NN, xout, 0L);
        else
            gemm_mfma<true, true, true, false><<<dim3(8, 64, 1), blk, 0, stream>>>(
                A, NN, ABATCH, bufA, (long)ND, 0L, bufC, Zs + 0 * BND, bias,
                1.f, -1.f, NN, xout, 0L);
    };

    // stage 1
    gemm_mfma<false, false, false, false><<<dim3(8, 64, 6), blk, 0, stream>>>(
        X, NN, ABATCH, W1t, 0L, (long)DD * NN, nullptr, nullptr, nullptr,
        1.f, 0.f, NN, Zs, BND);
    cheb(b1v, bufB, false);
    ln_pool<<<dim3(64), blk, 0, stream>>>(bufB, g1, bt1, hbuf, zfeat, 0);

    // stage 2
    gemm_mfma<false, false, false, false><<<dim3(8, 64, 6), blk, 0, stream>>>(
        hbuf, DD, (long)ND, W2t, 0L, (long)DD * DD, nullptr, nullptr, nullptr,
        1.f, 0.f, DD, Zs, BND);
    cheb(b2v, bufB, false);
    ln_pool<<<dim3(64), blk, 0, stream>>>(bufB, g2, bt2, hbuf, zfeat, 128);

    // stage 3: X0 (row-major) -> hbuf (h already consumed)
    gemm_mfma<false, false, false, false><<<dim3(8, 64, 6), blk, 0, stream>>>(
        hbuf, DD, (long)ND, W3t, 0L, (long)DD * DD, nullptr, nullptr, nullptr,
        1.f, 0.f, DD, Zs, BND);
    cheb(b3v, hbuf, true);

    // AE
    outer_mfma<<<dim3(8, 8, 64), blk, 0, stream>>>(hbuf, out);

    // heads
    heads<<<dim3(64), dim3(64), 0, stream>>>(
        zfeat, p1w, p1b, p2w, p2b, p3w, p3b, s1w, s1b, s2w, s2b, p4w, p4b, outc, outsc);
}